// Round 4
// baseline (3507.362 us; speedup 1.0000x reference)
//
#include <hip/hip_runtime.h>
#include <stdint.h>

#define T_STEPS 512
#define BATCH   256
#define INP     128
#define HID     512
#define BGN     16   // batch groups (16 rows each)
#define CGN     4    // column groups (128 cols each)  [r4: was 8]
#define RB      16   // rows per block
#define CB      128  // h-cols per block (16 per wave, 8 waves)
#define ZP      644  // LDS z row pitch in u16 (640 + 4 pad)

typedef float f32x4 __attribute__((ext_vector_type(4)));
typedef short s16x8 __attribute__((ext_vector_type(8)));
typedef unsigned short u16;
typedef unsigned int   u32;
typedef unsigned long long u64;

__device__ __forceinline__ u32 f2bf(float f) {
  union { float f; u32 u; } v; v.f = f;
  return (v.u + 0x7fffu + ((v.u >> 16) & 1u)) >> 16;  // RNE, bits in low 16
}

__device__ __forceinline__ float bf2f(u16 b) {
  union { u32 u; float f; } v; v.u = ((u32)b) << 16;
  return v.f;
}

// d_ws: hb[4][BATCH][HID] bf16 ring (1 MB), memset 0xFF (poison = bf16 -NaN,
// unreachable: |h| < 1.01 by the bounded ODE dynamics).
//
// Sentinel protocol (r2/r3-proven; r4 changes GEOMETRY only):
//   step t reads buffer t&3 (spin until non-poison), writes h(t+1) into
//   buffer (t+1)&3, re-poisons own slice of buffer (t+2)&3. vmcnt(0)
//   before the h stores orders poison < h-data at the MALL. Ring skew is
//   bounded by 1 step => mod-4 buffer reuse is race-free (same proof as r3).
//
// r4: ring degree 8 -> 4 (CGN=4, 512-thread blocks, 8 waves). Each thread
// polls exactly 3 granules (1 per peer). Rationale: the measured ~7100
// cy/step across three protocol variants is detect-tail dominated (round-
// quantized polling x max-over-granules into barrier2 x max-of-ring
// re-sync); degree/granule reduction attacks all three factors. Per-wave
// compute (16 cols, reg-resident weights, MFMA layout) is identical to r3.

__global__ __launch_bounds__(512, 2)
void liquid_persistent(const float* __restrict__ x_seq,
                       const float* __restrict__ Wc, const float* __restrict__ bc,
                       const float* __restrict__ Wt, const float* __restrict__ bt,
                       const float* __restrict__ Wo, const float* __restrict__ bo,
                       float* __restrict__ y_out, float* __restrict__ tau_out,
                       u16* __restrict__ hb)
{
  const int tid  = threadIdx.x;
  const int l    = tid & 63;
  const int w    = tid >> 6;          // wave 0..7
  const int quad = l >> 4;
  const int ln   = l & 15;
  const int bg   = blockIdx.x & (BGN - 1);
  const int cg   = blockIdx.x >> 4;   // 0..3
  const int R0   = bg * RB;
  const int C0   = cg * CB;
  const int cn   = C0 + w * 16 + ln;  // this lane's output column (both matrices)

  __shared__ u16 zS[RB][ZP];          // [x(128) ; h(512)] bf16 per row
  __shared__ float ypS[8];            // y partials (one per wave)

  // ---- register-resident weights: BOTH matrices for this wave's 16 cols ----
  s16x8 wfC[20], wfT[20];
#pragma unroll
  for (int kt = 0; kt < 20; ++kt) {
#pragma unroll
    for (int j = 0; j < 8; ++j) {
      int k = kt * 32 + quad * 8 + j;
      wfC[kt][j] = (short)f2bf(Wc[k * HID + cn]);
      wfT[kt][j] = (short)f2bf(Wt[k * HID + cn]);
    }
  }

  const float bcv = bc[cn], btv = bt[cn];
  const float bov = bo[0];
  float hm[4] = {0.f, 0.f, 0.f, 0.f};

  const int xrow = tid >> 5;   // staging row 0..15 (32 threads/row)
  const int xseg = tid & 31;   // 8B granule within row

  // y-compute: wave w -> local row w>>1 (block owns rows 4cg..4cg+3),
  // half (w&1); lane covers 4 cols.
  const int yrow = 4 * cg + (w >> 1);
  const int yc0  = (w & 1) * 256 + l * 4;
  const float4 wo4 = *(const float4*)&Wo[yc0];

  // peer column-group indices (skip own)
  int ii[3];
#pragma unroll
  for (int jx = 0; jx < 3; ++jx) ii[jx] = jx + (jx >= cg ? 1 : 0);

  const size_t rowq = HID / 4;                  // u64 per h row (=128)
  u64* hbase = (u64*)(void*)hb;
  const size_t myrow = (size_t)(R0 + xrow) * rowq;

  // ---- pre-stage x(0) into zS.x (one float4 -> one u64 per thread) ----
  {
    const float* xp = x_seq + ((size_t)0 * BATCH + R0 + xrow) * INP + xseg * 4;
    float4 a = *(const float4*)xp;
    u64 w0 = (u64)f2bf(a.x) | ((u64)f2bf(a.y) << 16) |
             ((u64)f2bf(a.z) << 32) | ((u64)f2bf(a.w) << 48);
    *(u64*)&zS[xrow][xseg * 4] = w0;
  }
  __syncthreads();

  for (int t = 0; t <= T_STEPS; ++t) {
    // per-thread poll addresses in buffer t&3 (3 peer granules, 1 per peer)
    const u64* rbase = hbase + (size_t)(t & 3) * BATCH * rowq + myrow + xseg;

    // ---- issue first sweep BEFORE Phase A (x-MFMAs hide the round trip) ----
    u64 tmp[3];
    if (t > 0) {
#pragma unroll
      for (int jx = 0; jx < 3; ++jx)
        tmp[jx] = __hip_atomic_load(rbase + ii[jx] * 32, __ATOMIC_RELAXED,
                                    __HIP_MEMORY_SCOPE_AGENT);
    }

    // ---- Phase A: x-part MFMAs (independent of h exchange) ----
    f32x4 aC0 = {0.f,0.f,0.f,0.f}, aC1 = {0.f,0.f,0.f,0.f};
    f32x4 aT0 = {0.f,0.f,0.f,0.f}, aT1 = {0.f,0.f,0.f,0.f};
    const u16* zb = &zS[ln][quad * 8];   // A layout: m=lane&15, k=quad*8+j
    if (t < T_STEPS) {
      s16x8 a0 = *(const s16x8*)(zb);
      s16x8 a1 = *(const s16x8*)(zb + 32);
      s16x8 a2 = *(const s16x8*)(zb + 64);
      s16x8 a3 = *(const s16x8*)(zb + 96);
      aC0 = __builtin_amdgcn_mfma_f32_16x16x32_bf16(a0, wfC[0], aC0, 0,0,0);
      aT0 = __builtin_amdgcn_mfma_f32_16x16x32_bf16(a0, wfT[0], aT0, 0,0,0);
      aC1 = __builtin_amdgcn_mfma_f32_16x16x32_bf16(a1, wfC[1], aC1, 0,0,0);
      aT1 = __builtin_amdgcn_mfma_f32_16x16x32_bf16(a1, wfT[1], aT1, 0,0,0);
      aC0 = __builtin_amdgcn_mfma_f32_16x16x32_bf16(a2, wfC[2], aC0, 0,0,0);
      aT0 = __builtin_amdgcn_mfma_f32_16x16x32_bf16(a2, wfT[2], aT0, 0,0,0);
      aC1 = __builtin_amdgcn_mfma_f32_16x16x32_bf16(a3, wfC[3], aC1, 0,0,0);
      aT1 = __builtin_amdgcn_mfma_f32_16x16x32_bf16(a3, wfT[3], aT1, 0,0,0);
    }

    // ---- resolve poll: granule valid iff neither dword is poison ----
    u64 hv[3];
    if (t == 0) {
#pragma unroll
      for (int jx = 0; jx < 3; ++jx) hv[jx] = 0;   // h(0) = 0
    } else {
      bool need[3];
      int pending = 0;
#pragma unroll
      for (int jx = 0; jx < 3; ++jx) {
        u64 v = tmp[jx];
        bool ok = ((u32)v != 0xFFFFFFFFu) && ((u32)(v >> 32) != 0xFFFFFFFFu);
        hv[jx] = v;
        need[jx] = !ok;
        pending += ok ? 0 : 1;
      }
      while (pending) {
        __builtin_amdgcn_s_sleep(1);   // backoff: decongest the MALL
#pragma unroll
        for (int jx = 0; jx < 3; ++jx)
          if (need[jx])
            tmp[jx] = __hip_atomic_load(rbase + ii[jx] * 32, __ATOMIC_RELAXED,
                                        __HIP_MEMORY_SCOPE_AGENT);
#pragma unroll
        for (int jx = 0; jx < 3; ++jx)
          if (need[jx]) {
            u64 v = tmp[jx];
            if (((u32)v != 0xFFFFFFFFu) && ((u32)(v >> 32) != 0xFFFFFFFFu)) {
              hv[jx] = v;
              need[jx] = false;
              --pending;
            }
          }
      }
    }

    // ---- re-poison own slice of buffer (t+2)&3 (ordered by vmcnt below) ----
    if (t < T_STEPS) {
      u64* pp = hbase + (size_t)((t + 2) & 3) * BATCH * rowq + myrow
              + (C0 / 4 + xseg);
      __hip_atomic_store(pp, ~0ull, __ATOMIC_RELAXED, __HIP_MEMORY_SCOPE_AGENT);
    }

    // ---- x(t+1) prefetch (consumed at staging, after Phase C) ----
    float4 xr0;
    if (t < T_STEPS) {
      const int tn = (t + 1 < T_STEPS) ? t + 1 : t;
      const float* xp = x_seq + ((size_t)tn * BATCH + R0 + xrow) * INP + xseg * 4;
      xr0 = *(const float4*)xp;
    }

    // ---- stage h into zS: 3 remote slices + own slice from registers ----
#pragma unroll
    for (int jx = 0; jx < 3; ++jx)
      *(u64*)&zS[xrow][INP + (ii[jx] * 32 + xseg) * 4] = hv[jx];
#pragma unroll
    for (int r = 0; r < 4; ++r)
      zS[quad * 4 + r][INP + cn] = (u16)f2bf(hm[r]);

    __syncthreads();   // barrier2: zS.h complete before Phase C / y-compute

    float tauv[4];
    if (t < T_STEPS) {
      // ---- Phase C: h-part MFMAs (4 independent accumulator chains) ----
#pragma unroll
      for (int kt = 4; kt < 20; kt += 2) {
        s16x8 a0 = *(const s16x8*)(zb + kt * 32);
        s16x8 a1 = *(const s16x8*)(zb + kt * 32 + 32);
        aC0 = __builtin_amdgcn_mfma_f32_16x16x32_bf16(a0, wfC[kt],   aC0, 0,0,0);
        aT0 = __builtin_amdgcn_mfma_f32_16x16x32_bf16(a0, wfT[kt],   aT0, 0,0,0);
        aC1 = __builtin_amdgcn_mfma_f32_16x16x32_bf16(a1, wfC[kt+1], aC1, 0,0,0);
        aT1 = __builtin_amdgcn_mfma_f32_16x16x32_bf16(a1, wfT[kt+1], aT1, 0,0,0);
      }
      aC0 += aC1;
      aT0 += aT1;

      // ---- stage x(t+1) into zS.x (all waves past Phase A via barrier2) ----
      u64 w0 = (u64)f2bf(xr0.x) | ((u64)f2bf(xr0.y) << 16) |
               ((u64)f2bf(xr0.z) << 32) | ((u64)f2bf(xr0.w) << 48);
      *(u64*)&zS[xrow][xseg * 4] = w0;

      // ---- Phase D: epilogue (C-layout: col=ln, row=quad*4+r) ----
#pragma unroll
      for (int r = 0; r < 4; ++r) {
        float pc = aC0[r] + bcv;
        float pt = aT0[r] + btv;
        pc = fminf(fmaxf(pc, -20.f), 20.f);
        float e  = __expf(2.f * pc);
        float cand = (e - 1.f) / (e + 1.f);          // tanh
        float tau  = 0.2f + 1.8f / (1.f + __expf(-pt));
        hm[r] += 0.1f * (cand - hm[r]) / tau;
        tauv[r] = tau;
      }

      // drain: orders the poison store before this step's h stores at the MALL
      asm volatile("s_waitcnt vmcnt(0)" ::: "memory");

      // ---- h store: pack 4 cols into one u64, lanes ln%4==0 store ----
#pragma unroll
      for (int r = 0; r < 4; ++r) {
        u32 bits = f2bf(hm[r]);
        u32 b0   = bits | ((u32)__shfl_xor((int)bits, 1) << 16);
        u64 q    = (u64)b0 | ((u64)(u32)__shfl_xor((int)b0, 2) << 32);
        if (!(ln & 3)) {
          u64* hp = hbase + (size_t)((t + 1) & 3) * BATCH * rowq
                  + (size_t)(R0 + quad * 4 + r) * rowq + (cn / 4);
          __hip_atomic_store(hp, q, __ATOMIC_RELAXED, __HIP_MEMORY_SCOPE_AGENT);
        }
      }
    }

    // ---- y(t-1) partials from staged zS.h (atomic-free; off store path) ----
    if (t > 0) {
      u64 hq = *(const u64*)&zS[yrow][INP + yc0];
      float py = bf2f((u16)hq)          * wo4.x
               + bf2f((u16)(hq >> 16))  * wo4.y
               + bf2f((u16)(hq >> 32))  * wo4.z
               + bf2f((u16)(hq >> 48))  * wo4.w;
      py += __shfl_down(py, 32);
      py += __shfl_down(py, 16);
      py += __shfl_down(py, 8);
      py += __shfl_down(py, 4);
      py += __shfl_down(py, 2);
      py += __shfl_down(py, 1);
      if (l == 0) ypS[w] = py;
    }

    __syncthreads();   // barrier3: zS.x staged + ypS complete

    if (t > 0 && tid < 4) {
      float yv = ypS[tid * 2] + ypS[tid * 2 + 1] + bov;
      y_out[(size_t)(t - 1) * BATCH + R0 + 4 * cg + tid] = yv;
    }

    // ---- tau tail (off the sync critical path) ----
    if (t < T_STEPS) {
#pragma unroll
      for (int r = 0; r < 4; ++r)
        __builtin_nontemporal_store(
            tauv[r],
            &tau_out[((size_t)t * BATCH + R0 + quad * 4 + r) * HID + cn]);
    }
  }
}

extern "C" void kernel_launch(void* const* d_in, const int* in_sizes, int n_in,
                              void* d_out, int out_size, void* d_ws, size_t ws_size,
                              hipStream_t stream) {
  (void)in_sizes; (void)n_in; (void)out_size; (void)ws_size;
  const float* x_seq = (const float*)d_in[0];
  const float* Wc    = (const float*)d_in[1];
  const float* bc    = (const float*)d_in[2];
  const float* Wt    = (const float*)d_in[3];
  const float* bt    = (const float*)d_in[4];
  const float* Wo    = (const float*)d_in[5];
  const float* bo    = (const float*)d_in[6];

  float* y_out   = (float*)d_out;                              // [T*B]
  float* tau_out = (float*)d_out + (size_t)T_STEPS * BATCH;    // [T*B*H]

  const size_t HB_BYTES = (size_t)4 * BATCH * HID * sizeof(u16); // 1 MB ring
  u16* hb = (u16*)d_ws;

  hipMemsetAsync(d_ws, 0xFF, HB_BYTES, stream);  // poison the whole ring

  liquid_persistent<<<dim3(BGN * CGN), dim3(512), 0, stream>>>(
      x_seq, Wc, bc, Wt, bt, Wo, bo, y_out, tau_out, hb);
}

// Round 5
// 3507.050 us; speedup vs baseline: 1.0001x; 1.0001x over previous
//
#include <hip/hip_runtime.h>
#include <stdint.h>

#define T_STEPS 512
#define BATCH   256
#define INP     128
#define HID     512
#define BGN     16   // batch groups (16 rows each)
#define CGN     4    // column groups (128 cols each)
#define RB      16   // rows per block
#define CB      128  // h-cols per block (16 per wave, 8 waves)
#define ZP      644  // LDS z row pitch in u16 (640 + 4 pad)

typedef float f32x4 __attribute__((ext_vector_type(4)));
typedef short s16x8 __attribute__((ext_vector_type(8)));
typedef unsigned short u16;
typedef unsigned int   u32;
typedef unsigned long long u64;

__device__ __forceinline__ u32 f2bf(float f) {
  union { float f; u32 u; } v; v.f = f;
  return (v.u + 0x7fffu + ((v.u >> 16) & 1u)) >> 16;  // RNE, bits in low 16
}

__device__ __forceinline__ float bf2f(u16 b) {
  union { u32 u; float f; } v; v.u = ((u32)b) << 16;
  return v.f;
}

// d_ws: hb[4][BATCH][HID] bf16 ring (1 MB), memset 0xFF (poison = bf16 -NaN,
// unreachable: |h| < 1.01 by the bounded ODE dynamics).
//
// Sentinel protocol (r2/r3-proven):
//   step t reads buffer t&3 (spin until non-poison), writes h(t+1) into
//   buffer (t+1)&3, re-poisons own slice of buffer (t+2)&3. vmcnt(0)
//   before the h stores orders poison < h-data at the MALL. Ring skew is
//   bounded by 1 step => mod-4 buffer reuse is race-free.
//
// r5 = r4 geometry (ring degree 4, 512-thread blocks, 1-granule-per-peer
// polls, conflict-free 32-thread-row staging) with the R4 bug fixed:
// __launch_bounds__(512, 1) -> 256-VGPR budget, so the 160-VGPR weight-
// stationary arrays stay in registers (R4's (512,2) capped VGPR at 128 and
// spilled the weights to scratch: VGPR_Count 184->128, dur 1730->3300).
// Also removed s_sleep backoff (quantized detect latency by ~64cy/round).
// Weight-stationary requires 32 waves x 160 weight-VGPRs per bg; 8-wave
// blocks at 2 waves/SIMD are the densest legal packing => CGN=4 is the
// minimum ring degree for this design.

__global__ __launch_bounds__(512, 1)
void liquid_persistent(const float* __restrict__ x_seq,
                       const float* __restrict__ Wc, const float* __restrict__ bc,
                       const float* __restrict__ Wt, const float* __restrict__ bt,
                       const float* __restrict__ Wo, const float* __restrict__ bo,
                       float* __restrict__ y_out, float* __restrict__ tau_out,
                       u16* __restrict__ hb)
{
  const int tid  = threadIdx.x;
  const int l    = tid & 63;
  const int w    = tid >> 6;          // wave 0..7
  const int quad = l >> 4;
  const int ln   = l & 15;
  const int bg   = blockIdx.x & (BGN - 1);
  const int cg   = blockIdx.x >> 4;   // 0..3
  const int R0   = bg * RB;
  const int C0   = cg * CB;
  const int cn   = C0 + w * 16 + ln;  // this lane's output column (both matrices)

  __shared__ u16 zS[RB][ZP];          // [x(128) ; h(512)] bf16 per row
  __shared__ float ypS[8];            // y partials (one per wave)

  // ---- register-resident weights: BOTH matrices for this wave's 16 cols ----
  s16x8 wfC[20], wfT[20];
#pragma unroll
  for (int kt = 0; kt < 20; ++kt) {
#pragma unroll
    for (int j = 0; j < 8; ++j) {
      int k = kt * 32 + quad * 8 + j;
      wfC[kt][j] = (short)f2bf(Wc[k * HID + cn]);
      wfT[kt][j] = (short)f2bf(Wt[k * HID + cn]);
    }
  }

  const float bcv = bc[cn], btv = bt[cn];
  const float bov = bo[0];
  float hm[4] = {0.f, 0.f, 0.f, 0.f};

  const int xrow = tid >> 5;   // staging row 0..15 (32 threads/row)
  const int xseg = tid & 31;   // 8B granule within row

  // y-compute: wave w -> local row w>>1 (block owns rows 4cg..4cg+3),
  // half (w&1); lane covers 4 cols.
  const int yrow = 4 * cg + (w >> 1);
  const int yc0  = (w & 1) * 256 + l * 4;
  const float4 wo4 = *(const float4*)&Wo[yc0];

  // peer column-group indices (skip own)
  int ii[3];
#pragma unroll
  for (int jx = 0; jx < 3; ++jx) ii[jx] = jx + (jx >= cg ? 1 : 0);

  const size_t rowq = HID / 4;                  // u64 per h row (=128)
  u64* hbase = (u64*)(void*)hb;
  const size_t myrow = (size_t)(R0 + xrow) * rowq;

  // ---- pre-stage x(0) into zS.x (one float4 -> one u64 per thread) ----
  {
    const float* xp = x_seq + ((size_t)0 * BATCH + R0 + xrow) * INP + xseg * 4;
    float4 a = *(const float4*)xp;
    u64 w0 = (u64)f2bf(a.x) | ((u64)f2bf(a.y) << 16) |
             ((u64)f2bf(a.z) << 32) | ((u64)f2bf(a.w) << 48);
    *(u64*)&zS[xrow][xseg * 4] = w0;
  }
  __syncthreads();

  for (int t = 0; t <= T_STEPS; ++t) {
    // per-thread poll addresses in buffer t&3 (3 peer granules, 1 per peer)
    const u64* rbase = hbase + (size_t)(t & 3) * BATCH * rowq + myrow + xseg;

    // ---- issue first sweep BEFORE Phase A (x-MFMAs hide the round trip) ----
    u64 tmp[3];
    if (t > 0) {
#pragma unroll
      for (int jx = 0; jx < 3; ++jx)
        tmp[jx] = __hip_atomic_load(rbase + ii[jx] * 32, __ATOMIC_RELAXED,
                                    __HIP_MEMORY_SCOPE_AGENT);
    }

    // ---- Phase A: x-part MFMAs (independent of h exchange) ----
    f32x4 aC0 = {0.f,0.f,0.f,0.f}, aC1 = {0.f,0.f,0.f,0.f};
    f32x4 aT0 = {0.f,0.f,0.f,0.f}, aT1 = {0.f,0.f,0.f,0.f};
    const u16* zb = &zS[ln][quad * 8];   // A layout: m=lane&15, k=quad*8+j
    if (t < T_STEPS) {
      s16x8 a0 = *(const s16x8*)(zb);
      s16x8 a1 = *(const s16x8*)(zb + 32);
      s16x8 a2 = *(const s16x8*)(zb + 64);
      s16x8 a3 = *(const s16x8*)(zb + 96);
      aC0 = __builtin_amdgcn_mfma_f32_16x16x32_bf16(a0, wfC[0], aC0, 0,0,0);
      aT0 = __builtin_amdgcn_mfma_f32_16x16x32_bf16(a0, wfT[0], aT0, 0,0,0);
      aC1 = __builtin_amdgcn_mfma_f32_16x16x32_bf16(a1, wfC[1], aC1, 0,0,0);
      aT1 = __builtin_amdgcn_mfma_f32_16x16x32_bf16(a1, wfT[1], aT1, 0,0,0);
      aC0 = __builtin_amdgcn_mfma_f32_16x16x32_bf16(a2, wfC[2], aC0, 0,0,0);
      aT0 = __builtin_amdgcn_mfma_f32_16x16x32_bf16(a2, wfT[2], aT0, 0,0,0);
      aC1 = __builtin_amdgcn_mfma_f32_16x16x32_bf16(a3, wfC[3], aC1, 0,0,0);
      aT1 = __builtin_amdgcn_mfma_f32_16x16x32_bf16(a3, wfT[3], aT1, 0,0,0);
    }

    // ---- resolve poll: granule valid iff neither dword is poison ----
    u64 hv[3];
    if (t == 0) {
#pragma unroll
      for (int jx = 0; jx < 3; ++jx) hv[jx] = 0;   // h(0) = 0
    } else {
      bool need[3];
      int pending = 0;
#pragma unroll
      for (int jx = 0; jx < 3; ++jx) {
        u64 v = tmp[jx];
        bool ok = ((u32)v != 0xFFFFFFFFu) && ((u32)(v >> 32) != 0xFFFFFFFFu);
        hv[jx] = v;
        need[jx] = !ok;
        pending += ok ? 0 : 1;
      }
      while (pending) {
#pragma unroll
        for (int jx = 0; jx < 3; ++jx)
          if (need[jx])
            tmp[jx] = __hip_atomic_load(rbase + ii[jx] * 32, __ATOMIC_RELAXED,
                                        __HIP_MEMORY_SCOPE_AGENT);
#pragma unroll
        for (int jx = 0; jx < 3; ++jx)
          if (need[jx]) {
            u64 v = tmp[jx];
            if (((u32)v != 0xFFFFFFFFu) && ((u32)(v >> 32) != 0xFFFFFFFFu)) {
              hv[jx] = v;
              need[jx] = false;
              --pending;
            }
          }
      }
    }

    // ---- re-poison own slice of buffer (t+2)&3 (ordered by vmcnt below) ----
    if (t < T_STEPS) {
      u64* pp = hbase + (size_t)((t + 2) & 3) * BATCH * rowq + myrow
              + (C0 / 4 + xseg);
      __hip_atomic_store(pp, ~0ull, __ATOMIC_RELAXED, __HIP_MEMORY_SCOPE_AGENT);
    }

    // ---- x(t+1) prefetch (consumed at staging, after Phase C) ----
    float4 xr0;
    if (t < T_STEPS) {
      const int tn = (t + 1 < T_STEPS) ? t + 1 : t;
      const float* xp = x_seq + ((size_t)tn * BATCH + R0 + xrow) * INP + xseg * 4;
      xr0 = *(const float4*)xp;
    }

    // ---- stage h into zS: 3 remote slices + own slice from registers ----
#pragma unroll
    for (int jx = 0; jx < 3; ++jx)
      *(u64*)&zS[xrow][INP + (ii[jx] * 32 + xseg) * 4] = hv[jx];
#pragma unroll
    for (int r = 0; r < 4; ++r)
      zS[quad * 4 + r][INP + cn] = (u16)f2bf(hm[r]);

    __syncthreads();   // barrier2: zS.h complete before Phase C / y-compute

    float tauv[4];
    if (t < T_STEPS) {
      // ---- Phase C: h-part MFMAs (4 independent accumulator chains) ----
#pragma unroll
      for (int kt = 4; kt < 20; kt += 2) {
        s16x8 a0 = *(const s16x8*)(zb + kt * 32);
        s16x8 a1 = *(const s16x8*)(zb + kt * 32 + 32);
        aC0 = __builtin_amdgcn_mfma_f32_16x16x32_bf16(a0, wfC[kt],   aC0, 0,0,0);
        aT0 = __builtin_amdgcn_mfma_f32_16x16x32_bf16(a0, wfT[kt],   aT0, 0,0,0);
        aC1 = __builtin_amdgcn_mfma_f32_16x16x32_bf16(a1, wfC[kt+1], aC1, 0,0,0);
        aT1 = __builtin_amdgcn_mfma_f32_16x16x32_bf16(a1, wfT[kt+1], aT1, 0,0,0);
      }
      aC0 += aC1;
      aT0 += aT1;

      // ---- stage x(t+1) into zS.x (all waves past Phase A via barrier2) ----
      u64 w0 = (u64)f2bf(xr0.x) | ((u64)f2bf(xr0.y) << 16) |
               ((u64)f2bf(xr0.z) << 32) | ((u64)f2bf(xr0.w) << 48);
      *(u64*)&zS[xrow][xseg * 4] = w0;

      // ---- Phase D: epilogue (C-layout: col=ln, row=quad*4+r) ----
#pragma unroll
      for (int r = 0; r < 4; ++r) {
        float pc = aC0[r] + bcv;
        float pt = aT0[r] + btv;
        pc = fminf(fmaxf(pc, -20.f), 20.f);
        float e  = __expf(2.f * pc);
        float cand = (e - 1.f) / (e + 1.f);          // tanh
        float tau  = 0.2f + 1.8f / (1.f + __expf(-pt));
        hm[r] += 0.1f * (cand - hm[r]) / tau;
        tauv[r] = tau;
      }

      // drain: orders the poison store before this step's h stores at the MALL
      asm volatile("s_waitcnt vmcnt(0)" ::: "memory");

      // ---- h store: pack 4 cols into one u64, lanes ln%4==0 store ----
#pragma unroll
      for (int r = 0; r < 4; ++r) {
        u32 bits = f2bf(hm[r]);
        u32 b0   = bits | ((u32)__shfl_xor((int)bits, 1) << 16);
        u64 q    = (u64)b0 | ((u64)(u32)__shfl_xor((int)b0, 2) << 32);
        if (!(ln & 3)) {
          u64* hp = hbase + (size_t)((t + 1) & 3) * BATCH * rowq
                  + (size_t)(R0 + quad * 4 + r) * rowq + (cn / 4);
          __hip_atomic_store(hp, q, __ATOMIC_RELAXED, __HIP_MEMORY_SCOPE_AGENT);
        }
      }
    }

    // ---- y(t-1) partials from staged zS.h (atomic-free; off store path) ----
    if (t > 0) {
      u64 hq = *(const u64*)&zS[yrow][INP + yc0];
      float py = bf2f((u16)hq)          * wo4.x
               + bf2f((u16)(hq >> 16))  * wo4.y
               + bf2f((u16)(hq >> 32))  * wo4.z
               + bf2f((u16)(hq >> 48))  * wo4.w;
      py += __shfl_down(py, 32);
      py += __shfl_down(py, 16);
      py += __shfl_down(py, 8);
      py += __shfl_down(py, 4);
      py += __shfl_down(py, 2);
      py += __shfl_down(py, 1);
      if (l == 0) ypS[w] = py;
    }

    __syncthreads();   // barrier3: zS.x staged + ypS complete

    if (t > 0 && tid < 4) {
      float yv = ypS[tid * 2] + ypS[tid * 2 + 1] + bov;
      y_out[(size_t)(t - 1) * BATCH + R0 + 4 * cg + tid] = yv;
    }

    // ---- tau tail (off the sync critical path) ----
    if (t < T_STEPS) {
#pragma unroll
      for (int r = 0; r < 4; ++r)
        __builtin_nontemporal_store(
            tauv[r],
            &tau_out[((size_t)t * BATCH + R0 + quad * 4 + r) * HID + cn]);
    }
  }
}

extern "C" void kernel_launch(void* const* d_in, const int* in_sizes, int n_in,
                              void* d_out, int out_size, void* d_ws, size_t ws_size,
                              hipStream_t stream) {
  (void)in_sizes; (void)n_in; (void)out_size; (void)ws_size;
  const float* x_seq = (const float*)d_in[0];
  const float* Wc    = (const float*)d_in[1];
  const float* bc    = (const float*)d_in[2];
  const float* Wt    = (const float*)d_in[3];
  const float* bt    = (const float*)d_in[4];
  const float* Wo    = (const float*)d_in[5];
  const float* bo    = (const float*)d_in[6];

  float* y_out   = (float*)d_out;                              // [T*B]
  float* tau_out = (float*)d_out + (size_t)T_STEPS * BATCH;    // [T*B*H]

  const size_t HB_BYTES = (size_t)4 * BATCH * HID * sizeof(u16); // 1 MB ring
  u16* hb = (u16*)d_ws;

  hipMemsetAsync(d_ws, 0xFF, HB_BYTES, stream);  // poison the whole ring

  liquid_persistent<<<dim3(BGN * CGN), dim3(512), 0, stream>>>(
      x_seq, Wc, bc, Wt, bt, Wo, bo, y_out, tau_out, hb);
}

// Round 6
// 1953.268 us; speedup vs baseline: 1.7956x; 1.7955x over previous
//
#include <hip/hip_runtime.h>
#include <stdint.h>

#define T_STEPS 512
#define BATCH   256
#define INP     128
#define HID     512
#define BGN     16   // batch groups (16 rows each)
#define CGN     8    // column groups (64 cols each)
#define RB      16   // rows per block
#define CB      64   // h-cols per block (16 per wave, 4 waves)
#define ZP      648  // LDS z row pitch in u16 (640 + 8 pad)

typedef float f32x4 __attribute__((ext_vector_type(4)));
typedef short s16x8 __attribute__((ext_vector_type(8)));
typedef unsigned short u16;
typedef unsigned int   u32;
typedef unsigned long long u64;

__device__ __forceinline__ u32 f2bf(float f) {
  union { float f; u32 u; } v; v.f = f;
  return (v.u + 0x7fffu + ((v.u >> 16) & 1u)) >> 16;  // RNE, bits in low 16
}

__device__ __forceinline__ float bf2f(u16 b) {
  union { u32 u; float f; } v; v.u = ((u32)b) << 16;
  return v.f;
}

// d_ws: hb[4][BATCH][HID] bf16 ring (1 MB) + canary int[BGN][CGN][16] (8 KB),
// all memset 0xFF (bf16 poison = -NaN, unreachable since |h| < 1.01; canary
// init = -1).
//
// Protocol (r3 sentinel + NEW per-wave canary):
//   step t: read buffer t&3; write h(t+1) into (t+1)&3; re-poison own slice
//   of (t+2)&3 (ordered before h-stores by the pre-store vmcnt(0)).
//   NEW: after its h-stores, each producer WAVE does s_waitcnt vmcnt(0)
//   (per-wave ack => its granules are AT the MALL) then stores canary = t+1.
//   Consumer: speculative data sweep at step top (accepted per-granule via
//   poison check, order-free) + canary sweep; spins only on 7 canaries
//   (granule xseg maps 1:1 to producer wave xseg>>2). canary >= t implies
//   that wave's h(t) granules are globally visible, so post-spin reloads
//   are trusted without re-polling (fence for load ordering). This replaces
//   the 1792-granule divergent retry tail with a 7-value deterministic
//   detect; in phase-locked steady state the spin body never runs.

__global__ __launch_bounds__(256, 1)
void liquid_persistent(const float* __restrict__ x_seq,
                       const float* __restrict__ Wc, const float* __restrict__ bc,
                       const float* __restrict__ Wt, const float* __restrict__ bt,
                       const float* __restrict__ Wo, const float* __restrict__ bo,
                       float* __restrict__ y_out, float* __restrict__ tau_out,
                       u16* __restrict__ hb, int* __restrict__ flags)
{
  const int tid  = threadIdx.x;
  const int l    = tid & 63;
  const int w    = tid >> 6;          // wave 0..3
  const int quad = l >> 4;
  const int ln   = l & 15;
  const int bg   = blockIdx.x & (BGN - 1);
  const int cg   = blockIdx.x >> 4;   // 0..7
  const int R0   = bg * RB;
  const int C0   = cg * CB;
  const int cn   = C0 + w * 16 + ln;  // this lane's output column (both matrices)

  __shared__ u16 zS[RB][ZP];          // [x(128) ; h(512)] bf16 per row
  __shared__ float ypS[4];            // y partials (one per wave)

  // ---- register-resident weights: BOTH matrices for this wave's 16 cols ----
  s16x8 wfC[20], wfT[20];
#pragma unroll
  for (int kt = 0; kt < 20; ++kt) {
#pragma unroll
    for (int j = 0; j < 8; ++j) {
      int k = kt * 32 + quad * 8 + j;
      wfC[kt][j] = (short)f2bf(Wc[k * HID + cn]);
      wfT[kt][j] = (short)f2bf(Wt[k * HID + cn]);
    }
  }

  const float bcv = bc[cn], btv = bt[cn];
  const float bov = bo[0];
  float hm[4] = {0.f, 0.f, 0.f, 0.f};

  const int xrow = tid >> 4;   // staging row 0..15
  const int xseg = tid & 15;
  const int cw   = xseg >> 2;  // producer WAVE of this thread's granules

  // y-compute mapping (r3): waves {0,1} -> local row 2cg, {2,3} -> 2cg+1.
  const int yrow = 2 * cg + (w >> 1);
  const int yc0  = (w & 1) * 256 + l * 4;
  const float4 wo4 = *(const float4*)&Wo[yc0];

  int ii[7];
#pragma unroll
  for (int jx = 0; jx < 7; ++jx) ii[jx] = jx + (jx >= cg ? 1 : 0);

  const size_t rowq = HID / 4;                  // u64 per h row
  u64* hbase = (u64*)(void*)hb;
  const size_t myrow = (size_t)(R0 + xrow) * rowq;

  // ---- pre-stage x(0) into zS.x ----
  {
    const float* xp = x_seq + ((size_t)0 * BATCH + R0 + xrow) * INP + xseg * 8;
    float4 a = *(const float4*)xp;
    float4 b = *(const float4*)(xp + 4);
    u64 w0 = (u64)f2bf(a.x) | ((u64)f2bf(a.y) << 16) |
             ((u64)f2bf(a.z) << 32) | ((u64)f2bf(a.w) << 48);
    u64 w1 = (u64)f2bf(b.x) | ((u64)f2bf(b.y) << 16) |
             ((u64)f2bf(b.z) << 32) | ((u64)f2bf(b.w) << 48);
    *(u64*)&zS[xrow][xseg * 8]     = w0;
    *(u64*)&zS[xrow][xseg * 8 + 4] = w1;
  }
  __syncthreads();

  for (int t = 0; t <= T_STEPS; ++t) {
    const u64* rbase = hbase + (size_t)(t & 3) * BATCH * rowq + myrow + xseg;

    // ---- top: speculative data sweep + canary sweep + x prefetch ----
    u64 tmp[7];
    int cvt[7];
    if (t > 0) {
#pragma unroll
      for (int jx = 0; jx < 7; ++jx)
        tmp[jx] = __hip_atomic_load(rbase + ii[jx] * 16, __ATOMIC_RELAXED,
                                    __HIP_MEMORY_SCOPE_AGENT);
#pragma unroll
      for (int jx = 0; jx < 7; ++jx)
        cvt[jx] = __hip_atomic_load(&flags[(bg * CGN + ii[jx]) * 16 + cw * 4],
                                    __ATOMIC_RELAXED, __HIP_MEMORY_SCOPE_AGENT);
    }
    float4 xr0, xr1;
    if (t < T_STEPS) {
      const int tn = (t + 1 < T_STEPS) ? t + 1 : t;
      const float* xp = x_seq + ((size_t)tn * BATCH + R0 + xrow) * INP + xseg * 8;
      xr0 = *(const float4*)xp;
      xr1 = *(const float4*)(xp + 4);
    }

    // ---- Phase A: x-part MFMAs (independent of h exchange) ----
    f32x4 aC0 = {0.f,0.f,0.f,0.f}, aC1 = {0.f,0.f,0.f,0.f};
    f32x4 aT0 = {0.f,0.f,0.f,0.f}, aT1 = {0.f,0.f,0.f,0.f};
    const u16* zb = &zS[ln][quad * 8];
    if (t < T_STEPS) {
      s16x8 a0 = *(const s16x8*)(zb);
      s16x8 a1 = *(const s16x8*)(zb + 32);
      s16x8 a2 = *(const s16x8*)(zb + 64);
      s16x8 a3 = *(const s16x8*)(zb + 96);
      aC0 = __builtin_amdgcn_mfma_f32_16x16x32_bf16(a0, wfC[0], aC0, 0,0,0);
      aT0 = __builtin_amdgcn_mfma_f32_16x16x32_bf16(a0, wfT[0], aT0, 0,0,0);
      aC1 = __builtin_amdgcn_mfma_f32_16x16x32_bf16(a1, wfC[1], aC1, 0,0,0);
      aT1 = __builtin_amdgcn_mfma_f32_16x16x32_bf16(a1, wfT[1], aT1, 0,0,0);
      aC0 = __builtin_amdgcn_mfma_f32_16x16x32_bf16(a2, wfC[2], aC0, 0,0,0);
      aT0 = __builtin_amdgcn_mfma_f32_16x16x32_bf16(a2, wfT[2], aT0, 0,0,0);
      aC1 = __builtin_amdgcn_mfma_f32_16x16x32_bf16(a3, wfC[3], aC1, 0,0,0);
      aT1 = __builtin_amdgcn_mfma_f32_16x16x32_bf16(a3, wfT[3], aT1, 0,0,0);
    }

    // ---- resolve ----
    u64 hv[7];
    if (t == 0) {
#pragma unroll
      for (int jx = 0; jx < 7; ++jx) hv[jx] = 0;   // h(0) = 0
    } else {
      bool need[7];
#pragma unroll
      for (int jx = 0; jx < 7; ++jx) {
        u64 v = tmp[jx];
        bool ok = ((u32)v != 0xFFFFFFFFu) && ((u32)(v >> 32) != 0xFFFFFFFFu);
        hv[jx] = v;
        need[jx] = !ok;
      }
      bool ready = true;
#pragma unroll
      for (int jx = 0; jx < 7; ++jx) ready = ready && (cvt[jx] >= t);
      while (!ready) {
#pragma unroll
        for (int jx = 0; jx < 7; ++jx)
          cvt[jx] = __hip_atomic_load(&flags[(bg * CGN + ii[jx]) * 16 + cw * 4],
                                      __ATOMIC_RELAXED, __HIP_MEMORY_SCOPE_AGENT);
#pragma unroll
        for (int jx = 0; jx < 7; ++jx)
          if (need[jx]) {
            u64 v = __hip_atomic_load(rbase + ii[jx] * 16, __ATOMIC_RELAXED,
                                      __HIP_MEMORY_SCOPE_AGENT);
            if (((u32)v != 0xFFFFFFFFu) && ((u32)(v >> 32) != 0xFFFFFFFFu)) {
              hv[jx] = v;
              need[jx] = false;
            }
          }
        ready = true;
#pragma unroll
        for (int jx = 0; jx < 7; ++jx) ready = ready && (cvt[jx] >= t);
      }
      // trusted final pass: canary >= t guarantees visibility of h(t)
      int pend = 0;
#pragma unroll
      for (int jx = 0; jx < 7; ++jx) pend += need[jx] ? 1 : 0;
      if (pend) {
        __threadfence();   // acquire: order reloads after canary observation
#pragma unroll
        for (int jx = 0; jx < 7; ++jx)
          if (need[jx])
            hv[jx] = __hip_atomic_load(rbase + ii[jx] * 16, __ATOMIC_RELAXED,
                                       __HIP_MEMORY_SCOPE_AGENT);
      }
    }

    // ---- re-poison own slice of buffer (t+2)&3 (drained pre-h-store) ----
    if (t < T_STEPS) {
      u64* pp = hbase + (size_t)((t + 2) & 3) * BATCH * rowq + myrow
              + (C0 / 4 + xseg);
      __hip_atomic_store(pp, ~0ull, __ATOMIC_RELAXED, __HIP_MEMORY_SCOPE_AGENT);
    }

    __syncthreads();   // barrier A: Phase-A reads / ypS writes done everywhere

    // ---- y(t-2) store from ypS written at step t-1's tail ----
    if (t >= 2 && tid < 2)
      y_out[(size_t)(t - 2) * BATCH + R0 + 2 * cg + tid] =
          ypS[tid * 2] + ypS[tid * 2 + 1] + bov;

    // ---- stage h into zS: 7 remote slices + own slice; stage x(t+1) ----
#pragma unroll
    for (int jx = 0; jx < 7; ++jx)
      *(u64*)&zS[xrow][INP + (ii[jx] * 16 + xseg) * 4] = hv[jx];
#pragma unroll
    for (int r = 0; r < 4; ++r)
      zS[quad * 4 + r][INP + cn] = (u16)f2bf(hm[r]);
    if (t < T_STEPS) {
      u64 w0 = (u64)f2bf(xr0.x) | ((u64)f2bf(xr0.y) << 16) |
               ((u64)f2bf(xr0.z) << 32) | ((u64)f2bf(xr0.w) << 48);
      u64 w1 = (u64)f2bf(xr1.x) | ((u64)f2bf(xr1.y) << 16) |
               ((u64)f2bf(xr1.z) << 32) | ((u64)f2bf(xr1.w) << 48);
      *(u64*)&zS[xrow][xseg * 8]     = w0;
      *(u64*)&zS[xrow][xseg * 8 + 4] = w1;
    }

    __syncthreads();   // barrier B: zS complete before Phase C / y-partials

    if (t < T_STEPS) {
      // ---- Phase C: h-part MFMAs ----
#pragma unroll
      for (int kt = 4; kt < 20; kt += 2) {
        s16x8 a0 = *(const s16x8*)(zb + kt * 32);
        s16x8 a1 = *(const s16x8*)(zb + kt * 32 + 32);
        aC0 = __builtin_amdgcn_mfma_f32_16x16x32_bf16(a0, wfC[kt],   aC0, 0,0,0);
        aT0 = __builtin_amdgcn_mfma_f32_16x16x32_bf16(a0, wfT[kt],   aT0, 0,0,0);
        aC1 = __builtin_amdgcn_mfma_f32_16x16x32_bf16(a1, wfC[kt+1], aC1, 0,0,0);
        aT1 = __builtin_amdgcn_mfma_f32_16x16x32_bf16(a1, wfT[kt+1], aT1, 0,0,0);
      }
      aC0 += aC1;
      aT0 += aT1;

      // ---- Phase D: epilogue ----
      float tauv[4];
#pragma unroll
      for (int r = 0; r < 4; ++r) {
        float pc = aC0[r] + bcv;
        float pt = aT0[r] + btv;
        pc = fminf(fmaxf(pc, -20.f), 20.f);
        float e  = __expf(2.f * pc);
        float cand = (e - 1.f) / (e + 1.f);          // tanh
        float tau  = 0.2f + 1.8f / (1.f + __expf(-pt));
        hm[r] += 0.1f * (cand - hm[r]) / tau;
        tauv[r] = tau;
      }

      // drain poison (+ any stragglers) before h-stores
      asm volatile("s_waitcnt vmcnt(0)" ::: "memory");

      // ---- h store: pack 4 cols into one u64, lanes ln%4==0 store ----
#pragma unroll
      for (int r = 0; r < 4; ++r) {
        u32 bits = f2bf(hm[r]);
        u32 b0   = bits | ((u32)__shfl_xor((int)bits, 1) << 16);
        u64 q    = (u64)b0 | ((u64)(u32)__shfl_xor((int)b0, 2) << 32);
        if (!(ln & 3)) {
          u64* hp = hbase + (size_t)((t + 1) & 3) * BATCH * rowq
                  + (size_t)(R0 + quad * 4 + r) * rowq + (cn / 4);
          __hip_atomic_store(hp, q, __ATOMIC_RELAXED, __HIP_MEMORY_SCOPE_AGENT);
        }
      }

      // per-WAVE release: drain this wave's h-stores, publish canary t+1
      asm volatile("s_waitcnt vmcnt(0)" ::: "memory");
      if (l == 0)
        __hip_atomic_store(&flags[(bg * CGN + cg) * 16 + w * 4], t + 1,
                           __ATOMIC_RELAXED, __HIP_MEMORY_SCOPE_AGENT);

      // ---- tau tail (off the sync critical path) ----
#pragma unroll
      for (int r = 0; r < 4; ++r)
        __builtin_nontemporal_store(
            tauv[r],
            &tau_out[((size_t)t * BATCH + R0 + quad * 4 + r) * HID + cn]);
    }

    // ---- y partials from staged zS.h (zS stable until next barrier A) ----
    {
      u64 hq = *(const u64*)&zS[yrow][INP + yc0];
      float py = bf2f((u16)hq)          * wo4.x
               + bf2f((u16)(hq >> 16))  * wo4.y
               + bf2f((u16)(hq >> 32))  * wo4.z
               + bf2f((u16)(hq >> 48))  * wo4.w;
      py += __shfl_down(py, 32);
      py += __shfl_down(py, 16);
      py += __shfl_down(py, 8);
      py += __shfl_down(py, 4);
      py += __shfl_down(py, 2);
      py += __shfl_down(py, 1);
      if (l == 0) ypS[w] = py;
    }
  }

  __syncthreads();
  if (tid < 2)
    y_out[(size_t)(T_STEPS - 1) * BATCH + R0 + 2 * cg + tid] =
        ypS[tid * 2] + ypS[tid * 2 + 1] + bov;
}

extern "C" void kernel_launch(void* const* d_in, const int* in_sizes, int n_in,
                              void* d_out, int out_size, void* d_ws, size_t ws_size,
                              hipStream_t stream) {
  (void)in_sizes; (void)n_in; (void)out_size; (void)ws_size;
  const float* x_seq = (const float*)d_in[0];
  const float* Wc    = (const float*)d_in[1];
  const float* bc    = (const float*)d_in[2];
  const float* Wt    = (const float*)d_in[3];
  const float* bt    = (const float*)d_in[4];
  const float* Wo    = (const float*)d_in[5];
  const float* bo    = (const float*)d_in[6];

  float* y_out   = (float*)d_out;                              // [T*B]
  float* tau_out = (float*)d_out + (size_t)T_STEPS * BATCH;    // [T*B*H]

  const size_t HB_BYTES   = (size_t)4 * BATCH * HID * sizeof(u16); // 1 MB ring
  const size_t FLAG_BYTES = (size_t)BGN * CGN * 16 * sizeof(int);  // 8 KB
  u16* hb    = (u16*)d_ws;
  int* flags = (int*)((char*)d_ws + HB_BYTES);

  // poison ring; canaries init to -1 (0xFFFFFFFF)
  hipMemsetAsync(d_ws, 0xFF, HB_BYTES + FLAG_BYTES, stream);

  liquid_persistent<<<dim3(BGN * CGN), dim3(256), 0, stream>>>(
      x_seq, Wc, bc, Wt, bt, Wo, bo, y_out, tau_out, hb, flags);
}